// Round 4
// baseline (310.173 us; speedup 1.0000x reference)
//
#include <hip/hip_runtime.h>

#define BN_EPS 1e-5f
typedef unsigned short u16;
typedef unsigned int u32;

// ws layout: stats = 72 floats at ws (sum1[28], ssq1[28], sum2[8], ssq2[8])
//   Psrc at ws+1024B : N*32 u16 (bf16, row stride 32, 28 used)   3.2 MB
//   Pdst next        : N*32 u16                                   3.2 MB
//   y1   next        : E*32 u16 (bf16, row stride 32, 28 used)   38.4 MB
//   y2   next        : E*8  u16 (bf16)                            9.6 MB

__device__ __forceinline__ u16 f2bf(float f) {
  u32 u = __float_as_uint(f);
  return (u16)((u + 0x7fffu + ((u >> 16) & 1u)) >> 16);  // RNE
}
__device__ __forceinline__ float bf2f(u16 s) {
  return __uint_as_float(((u32)s) << 16);
}
__device__ __forceinline__ u32 pack2(float a, float b) {
  return (u32)f2bf(a) | ((u32)f2bf(b) << 16);
}

// K1: per-node projection (R2-proven structure), output bf16 rows padded to 64B.
// half=0 -> Psrc (W1 cols 0..127), half=1 -> Pdst (W1 cols 128..255).
// Also zeroes stats[0..72).
__global__ void k1_proj(const float* __restrict__ h, const float* __restrict__ W1,
                        u16* __restrict__ Psrc, u16* __restrict__ Pdst,
                        float* __restrict__ stats, int N) {
  if (blockIdx.x == 0 && threadIdx.x < 72) stats[threadIdx.x] = 0.f;
  const int half = blockIdx.x & 1;
  const int node = (blockIdx.x >> 1) * 256 + threadIdx.x;
  if (node >= N) return;
  const float* __restrict__ wbase = W1 + half * 128;
  const float4* __restrict__ h4 = (const float4*)(h + (size_t)node * 128);
  float acc[28];
#pragma unroll
  for (int c = 0; c < 28; c++) acc[c] = 0.f;
  for (int kk = 0; kk < 16; kk++) {
    const float4 a = h4[kk * 2];
    const float4 b = h4[kk * 2 + 1];
#pragma unroll
    for (int c = 0; c < 28; c++) {
      const float* w = wbase + c * 268 + kk * 8;  // wave-uniform -> s_load
      acc[c] += a.x * w[0] + a.y * w[1] + a.z * w[2] + a.w * w[3]
              + b.x * w[4] + b.y * w[5] + b.z * w[6] + b.w * w[7];
    }
  }
  u16* out = (half == 0 ? Psrc : Pdst) + (size_t)node * 32;
  u32 u[14];
#pragma unroll
  for (int j = 0; j < 14; j++) u[j] = pack2(acc[2 * j], acc[2 * j + 1]);
  uint4* p4 = (uint4*)out;                       // 64B-aligned row
  p4[0] = make_uint4(u[0], u[1], u[2], u[3]);
  p4[1] = make_uint4(u[4], u[5], u[6], u[7]);
  p4[2] = make_uint4(u[8], u[9], u[10], u[11]);
  *(uint2*)((u32*)out + 12) = make_uint2(u[12], u[13]);
}

// K2: layer 1. Half-wave per edge (R2-proven pattern): lane c<28 owns channel c.
// bf16 single-line gathers from Psrc/Pdst; y1 stored bf16, row stride 32.
__global__ void k2_l1(const u16* __restrict__ Psrc, const u16* __restrict__ Pdst,
                      const float* __restrict__ ef,
                      const int* __restrict__ src, const int* __restrict__ dst,
                      const float* __restrict__ W1, const float* __restrict__ b1,
                      u16* __restrict__ y1, float* __restrict__ stats, int E) {
  const int tid = threadIdx.x;
  const int c = tid & 31;
  const int g = tid >> 5;
  const bool act = (c < 28);
  float w[12];
  float bias = 0.f;
  if (act) {
    const float4* wp = (const float4*)(W1 + c * 268 + 256);  // 16B aligned
    float4 w0 = wp[0], w1 = wp[1], w2 = wp[2];
    w[0] = w0.x; w[1] = w0.y; w[2] = w0.z; w[3] = w0.w;
    w[4] = w1.x; w[5] = w1.y; w[6] = w1.z; w[7] = w1.w;
    w[8] = w2.x; w[9] = w2.y; w[10] = w2.z; w[11] = w2.w;
    bias = b1[c];
  }
  float sum = 0.f, ssq = 0.f;
  const int gstride = gridDim.x * 8;
  for (int e = blockIdx.x * 8 + g; e < E; e += gstride) {
    const int s = src[e], d = dst[e];
    if (act) {
      const float pa = bf2f(Psrc[(size_t)s * 32 + c]);
      const float pb = bf2f(Pdst[(size_t)d * 32 + c]);
      const float4* e4 = (const float4*)(ef + (size_t)e * 12);
      float4 f0 = e4[0], f1 = e4[1], f2 = e4[2];
      const float y = bias
          + f0.x * w[0] + f0.y * w[1] + f0.z * w[2] + f0.w * w[3]
          + f1.x * w[4] + f1.y * w[5] + f1.z * w[6] + f1.w * w[7]
          + f2.x * w[8] + f2.y * w[9] + f2.z * w[10] + f2.w * w[11]
          + pa + pb;
      y1[(size_t)e * 32 + c] = f2bf(y);
      sum += y;
      ssq += y * y;
    }
  }
  sum += __shfl_xor(sum, 32);
  ssq += __shfl_xor(ssq, 32);
  __shared__ float red[2][4][28];
  const int wave = tid >> 6, lane = tid & 63;
  if (lane < 28) { red[0][wave][lane] = sum; red[1][wave][lane] = ssq; }
  __syncthreads();
  if (tid < 28) {
    atomicAdd(&stats[tid], red[0][0][tid] + red[0][1][tid] + red[0][2][tid] + red[0][3][tid]);
    atomicAdd(&stats[28 + tid], red[1][0][tid] + red[1][1][tid] + red[1][2][tid] + red[1][3][tid]);
  }
}

// K4: BN1 coefs per-thread from stats, then s1=relu(BN1(y1)), y2=s1@W2.T+b2 (bf16),
// accumulate stats2 (R2-proven reduction).
__global__ void k4_l2(const u16* __restrict__ y1, const float* __restrict__ stats,
                      const float* __restrict__ g1, const float* __restrict__ be1,
                      const float* __restrict__ W2, const float* __restrict__ b2,
                      u16* __restrict__ y2, float* __restrict__ stats2, int E, float invE) {
  float sc[28], sh[28];
#pragma unroll
  for (int cc = 0; cc < 28; cc++) {
    const float m = stats[cc] * invE;
    const float v = stats[28 + cc] * invE - m * m;
    const float s = g1[cc] * rsqrtf(v + BN_EPS);
    sc[cc] = s; sh[cc] = be1[cc] - m * s;
  }
  float as[8], aq[8];
#pragma unroll
  for (int o = 0; o < 8; o++) { as[o] = 0.f; aq[o] = 0.f; }
  const int stride = gridDim.x * blockDim.x;
  for (int e = blockIdx.x * blockDim.x + threadIdx.x; e < E; e += stride) {
    const u16* row = y1 + (size_t)e * 32;       // 64B-aligned
    const uint4 r0 = *(const uint4*)row;
    const uint4 r1 = *(const uint4*)(row + 8);
    const uint4 r2 = *(const uint4*)(row + 16);
    const uint2 r3 = *(const uint2*)(row + 24);
    u32 uu[14] = {r0.x, r0.y, r0.z, r0.w, r1.x, r1.y, r1.z, r1.w,
                  r2.x, r2.y, r2.z, r2.w, r3.x, r3.y};
    float acc[8];
#pragma unroll
    for (int o = 0; o < 8; o++) acc[o] = b2[o];
#pragma unroll
    for (int k = 0; k < 14; k++) {
      const float fe = __uint_as_float(uu[k] << 16);
      const float fo = __uint_as_float(uu[k] & 0xffff0000u);
      const float se = fmaxf(fmaf(fe, sc[2 * k], sh[2 * k]), 0.f);
      const float so = fmaxf(fmaf(fo, sc[2 * k + 1], sh[2 * k + 1]), 0.f);
#pragma unroll
      for (int o = 0; o < 8; o++) {
        acc[o] = fmaf(W2[o * 28 + 2 * k], se, acc[o]);      // uniform -> s_load
        acc[o] = fmaf(W2[o * 28 + 2 * k + 1], so, acc[o]);
      }
    }
    *(uint4*)(y2 + (size_t)e * 8) = make_uint4(pack2(acc[0], acc[1]), pack2(acc[2], acc[3]),
                                               pack2(acc[4], acc[5]), pack2(acc[6], acc[7]));
#pragma unroll
    for (int o = 0; o < 8; o++) { as[o] += acc[o]; aq[o] += acc[o] * acc[o]; }
  }
#pragma unroll
  for (int o = 0; o < 8; o++) {
    for (int off = 32; off; off >>= 1) {
      as[o] += __shfl_down(as[o], off);
      aq[o] += __shfl_down(aq[o], off);
    }
  }
  __shared__ float redS[4][16];
  const int wave = threadIdx.x >> 6, lane = threadIdx.x & 63;
  if (lane == 0) {
#pragma unroll
    for (int o = 0; o < 8; o++) { redS[wave][o] = as[o]; redS[wave][8 + o] = aq[o]; }
  }
  __syncthreads();
  if (threadIdx.x < 16) {
    const int t = threadIdx.x;
    atomicAdd(&stats2[t], redS[0][t] + redS[1][t] + redS[2][t] + redS[3][t]);
  }
}

// K6: BN2 coefs per-thread, out = relu(BN2(y2)) @ W3.T + b3
__global__ void k6_l3(const u16* __restrict__ y2, const float* __restrict__ stats,
                      const float* __restrict__ g2, const float* __restrict__ be2,
                      const float* __restrict__ W3, const float* __restrict__ b3,
                      float* __restrict__ out, int E, float invE) {
  float sc[8], sh[8], w3[8];
#pragma unroll
  for (int o = 0; o < 8; o++) {
    const float m = stats[56 + o] * invE;
    const float v = stats[64 + o] * invE - m * m;
    const float s = g2[o] * rsqrtf(v + BN_EPS);
    sc[o] = s; sh[o] = be2[o] - m * s; w3[o] = W3[o];
  }
  const int e = blockIdx.x * blockDim.x + threadIdx.x;
  if (e >= E) return;
  const uint4 r = *(const uint4*)(y2 + (size_t)e * 8);
  u32 uu[4] = {r.x, r.y, r.z, r.w};
  float acc = b3[0];
#pragma unroll
  for (int k = 0; k < 4; k++) {
    const float fe = __uint_as_float(uu[k] << 16);
    const float fo = __uint_as_float(uu[k] & 0xffff0000u);
    acc = fmaf(w3[2 * k], fmaxf(fmaf(fe, sc[2 * k], sh[2 * k]), 0.f), acc);
    acc = fmaf(w3[2 * k + 1], fmaxf(fmaf(fo, sc[2 * k + 1], sh[2 * k + 1]), 0.f), acc);
  }
  out[e] = acc;
}

extern "C" void kernel_launch(void* const* d_in, const int* in_sizes, int n_in,
                              void* d_out, int out_size, void* d_ws, size_t ws_size,
                              hipStream_t stream) {
  const float* h   = (const float*)d_in[0];
  const float* ef  = (const float*)d_in[1];
  const int* src   = (const int*)d_in[2];
  const int* dst   = (const int*)d_in[3];
  const float* W1  = (const float*)d_in[4];
  const float* b1  = (const float*)d_in[5];
  const float* g1  = (const float*)d_in[6];
  const float* be1 = (const float*)d_in[7];
  const float* W2  = (const float*)d_in[8];
  const float* b2  = (const float*)d_in[9];
  const float* g2  = (const float*)d_in[10];
  const float* be2 = (const float*)d_in[11];
  const float* W3  = (const float*)d_in[12];
  const float* b3  = (const float*)d_in[13];
  float* out = (float*)d_out;

  const int N = in_sizes[0] / 128;
  const int E = in_sizes[2];
  const float invE = 1.0f / (float)E;

  char* ws = (char*)d_ws;
  float* stats = (float*)ws;                       // 72 floats
  u16* Psrc = (u16*)(ws + 1024);
  u16* Pdst = Psrc + (size_t)N * 32;
  u16* y1   = Pdst + (size_t)N * 32;
  u16* y2   = y1 + (size_t)E * 32;

  const int nodeBlocks = (N + 255) / 256;
  k1_proj<<<nodeBlocks * 2, 256, 0, stream>>>(h, W1, Psrc, Pdst, stats, N);
  k2_l1<<<2560, 256, 0, stream>>>(Psrc, Pdst, ef, src, dst, W1, b1, y1, stats, E);
  k4_l2<<<1172, 256, 0, stream>>>(y1, stats, g1, be1, W2, b2, y2, stats + 56, E, invE);
  k6_l3<<<(E + 255) / 256, 256, 0, stream>>>(y2, stats, g2, be2, W3, b3, out, E, invE);
}